// Round 2
// baseline (276.764 us; speedup 1.0000x reference)
//
#include <hip/hip_runtime.h>
#include <cstdint>
#include <cstddef>

#define EMB   256
#define NA    16384
#define NOBJ  32768
#define E1CNT 131072
#define E2CNT 262144
#define NDEC  1056
#define NDECP 1152
#define DEC_OFF ((size_t)NA * NDEC)

typedef unsigned short u16;
typedef __attribute__((ext_vector_type(8))) short bf16x8;
typedef __attribute__((ext_vector_type(8))) unsigned short u16x8;
typedef __attribute__((ext_vector_type(4))) float f32x4;

// ---------------------------------------------------------------------------
// bf16 helpers (RNE)
// ---------------------------------------------------------------------------
__device__ __forceinline__ u16 f2bf(float f) {
  union { float f; unsigned u; } x; x.f = f;
  unsigned u = x.u + 0x7FFFu + ((x.u >> 16) & 1u);
  return (u16)(u >> 16);
}
__device__ __forceinline__ float bf2f(u16 h) {
  union { unsigned u; float f; } x; x.u = ((unsigned)h) << 16;
  return x.f;
}

__device__ __forceinline__ void gload_lds16(const void* g, void* l) {
  __builtin_amdgcn_global_load_lds(
      (const __attribute__((address_space(1))) unsigned int*)g,
      (__attribute__((address_space(3))) unsigned int*)l, 16, 0, 0);
}

// ---------------------------------------------------------------------------
// inline segment reduce: a0..a3 = sum_e relu(vals[idx[e]][lane*4+r] - t_r)
// 4-deep unrolled gathers (MLP=4) with two accumulator chains
// ---------------------------------------------------------------------------
__device__ __forceinline__ void seg_reduce_row(
    const u16* __restrict__ vals, const int* __restrict__ idx,
    int e0, int e1, int lane,
    float t0, float t1, float t2, float t3,
    float& r0, float& r1, float& r2, float& r3)
{
  float a0 = 0.f, a1 = 0.f, a2 = 0.f, a3 = 0.f;
  float b0 = 0.f, b1 = 0.f, b2 = 0.f, b3 = 0.f;
  int i = e0;
  for (; i + 3 < e1; i += 4) {
    const int o0 = idx[i], o1 = idx[i + 1], o2 = idx[i + 2], o3 = idx[i + 3];
    const ushort4 z0 = *(const ushort4*)(vals + (size_t)o0 * 256 + lane * 4);
    const ushort4 z1 = *(const ushort4*)(vals + (size_t)o1 * 256 + lane * 4);
    const ushort4 z2 = *(const ushort4*)(vals + (size_t)o2 * 256 + lane * 4);
    const ushort4 z3 = *(const ushort4*)(vals + (size_t)o3 * 256 + lane * 4);
    a0 += fmaxf(bf2f(z0.x) - t0, 0.f); a1 += fmaxf(bf2f(z0.y) - t1, 0.f);
    a2 += fmaxf(bf2f(z0.z) - t2, 0.f); a3 += fmaxf(bf2f(z0.w) - t3, 0.f);
    b0 += fmaxf(bf2f(z1.x) - t0, 0.f); b1 += fmaxf(bf2f(z1.y) - t1, 0.f);
    b2 += fmaxf(bf2f(z1.z) - t2, 0.f); b3 += fmaxf(bf2f(z1.w) - t3, 0.f);
    a0 += fmaxf(bf2f(z2.x) - t0, 0.f); a1 += fmaxf(bf2f(z2.y) - t1, 0.f);
    a2 += fmaxf(bf2f(z2.z) - t2, 0.f); a3 += fmaxf(bf2f(z2.w) - t3, 0.f);
    b0 += fmaxf(bf2f(z3.x) - t0, 0.f); b1 += fmaxf(bf2f(z3.y) - t1, 0.f);
    b2 += fmaxf(bf2f(z3.z) - t2, 0.f); b3 += fmaxf(bf2f(z3.w) - t3, 0.f);
  }
  for (; i < e1; ++i) {
    const int o = idx[i];
    const ushort4 z = *(const ushort4*)(vals + (size_t)o * 256 + lane * 4);
    a0 += fmaxf(bf2f(z.x) - t0, 0.f); a1 += fmaxf(bf2f(z.y) - t1, 0.f);
    a2 += fmaxf(bf2f(z.z) - t2, 0.f); a3 += fmaxf(bf2f(z.w) - t3, 0.f);
  }
  r0 = a0 + b0; r1 = a1 + b1; r2 = a2 + b2; r3 = a3 + b3;
}

// ---------------------------------------------------------------------------
// front: CSR count + obj prep (bf16, 8-wide) + all weight cvt/transpose
// blocks [0,1536): count | [1536,3072): prep | [3072,3356): cvt
// ---------------------------------------------------------------------------
__global__ __launch_bounds__(256) void k_front(
    const int* __restrict__ k1, const int* __restrict__ k2,
    int* __restrict__ c1, int* __restrict__ c2,
    const float* __restrict__ obj_x, const float* __restrict__ obj_pos,
    u16* __restrict__ Aobj,
    const float* __restrict__ W1, const float* __restrict__ W2,
    const float* __restrict__ Wm, const float* __restrict__ Wu,
    const float* __restrict__ Wd,
    u16* __restrict__ w1t, u16* __restrict__ w2t, u16* __restrict__ wmt,
    u16* __restrict__ wut, u16* __restrict__ wdt)
{
  const int b = blockIdx.x, tid = threadIdx.x;
  if (b < 1536) {                                  // edge counting
    const int e = b * 256 + tid;
    if (e < E1CNT) atomicAdd(&c1[k1[e]], 1);
    else           atomicAdd(&c2[k2[e - E1CNT]], 1);
    return;
  }
  if (b < 3072) {                                  // Aobj[o][96] = [x|pos|0]
    const int g = (b - 1536) * 256 + tid;
    const int row = g / 12, seg = g - row * 12;
    u16x8 o;
    if (seg < 8) {
      const float4 f0 = *(const float4*)(obj_x + (size_t)row * 64 + seg * 8);
      const float4 f1 = *(const float4*)(obj_x + (size_t)row * 64 + seg * 8 + 4);
      o[0] = f2bf(f0.x); o[1] = f2bf(f0.y); o[2] = f2bf(f0.z); o[3] = f2bf(f0.w);
      o[4] = f2bf(f1.x); o[5] = f2bf(f1.y); o[6] = f2bf(f1.z); o[7] = f2bf(f1.w);
    } else if (seg == 8) {
      const float2 pp = *(const float2*)(obj_pos + (size_t)row * 2);
      o[0] = f2bf(pp.x); o[1] = f2bf(pp.y);
      o[2] = 0; o[3] = 0; o[4] = 0; o[5] = 0; o[6] = 0; o[7] = 0;
    } else {
#pragma unroll
      for (int t = 0; t < 8; ++t) o[t] = 0;
    }
    *(u16x8*)(Aobj + (size_t)row * 96 + seg * 8) = o;
    return;
  }
  // weight transpose+cvt; boundaries in 8-elem units
  int l = (b - 3072) * 256 + tid;
  const float* W; u16* WT; int Ko, No, Kp8;
  if      (l < 3072)  { W = W1; WT = w1t; Ko = 66;  No = 256;  Kp8 = 12; }
  else if (l < 11264) { W = W2; WT = w2t; Ko = 256; No = 256;  Kp8 = 32; l -= 3072; }
  else if (l < 19456) { W = Wm; WT = wmt; Ko = 256; No = 256;  Kp8 = 32; l -= 11264; }
  else if (l < 35840) { W = Wu; WT = wut; Ko = 512; No = 256;  Kp8 = 64; l -= 19456; }
  else                { W = Wd; WT = wdt; Ko = 256; No = 1056; Kp8 = 32; l -= 35840; }
  const int n = l / Kp8, k0 = (l - n * Kp8) * 8;
  u16x8 o;
#pragma unroll
  for (int t = 0; t < 8; ++t) {
    const int k = k0 + t;
    const float v = (k < Ko && n < No) ? W[(size_t)k * No + n] : 0.f;
    o[t] = f2bf(v);
  }
  *(u16x8*)(WT + (size_t)n * (Kp8 * 8) + k0) = o;
}

// ---------------------------------------------------------------------------
// prefix scan of both count arrays
// ---------------------------------------------------------------------------
__global__ __launch_bounds__(256) void k_scan(int* c1, int* r1, int* c2, int* r2) {
  int* cnt = (blockIdx.x == 0) ? c1 : c2;
  int* rp  = (blockIdx.x == 0) ? r1 : r2;
  const int n = NA;
  __shared__ int partial[256];
  const int tid = threadIdx.x;
  const int base = tid * 64;
  int local[64];
  int s = 0;
#pragma unroll
  for (int i = 0; i < 64; ++i) { local[i] = s; s += cnt[base + i]; }
  partial[tid] = s;
  __syncthreads();
  for (int off = 1; off < 256; off <<= 1) {
    int v = (tid >= off) ? partial[tid - off] : 0;
    __syncthreads();
    partial[tid] += v;
    __syncthreads();
  }
  const int offset = (tid == 0) ? 0 : partial[tid - 1];
#pragma unroll
  for (int i = 0; i < 64; ++i) {
    int v = offset + local[i];
    rp[base + i]  = v;
    cnt[base + i] = v;
  }
  if (tid == 255) rp[n] = partial[255];
}

// ---------------------------------------------------------------------------
// fill CSR + encode GEMM (zobj = [obj_x|obj_pos|0] @ W1 + b1) in ONE dispatch
// 256-thread blocks: [0,1536) fill | [1536,2048): 128x128 GEMM tiles (M x Nhalf)
// ---------------------------------------------------------------------------
__global__ __launch_bounds__(256) void k_fill_enc(
    const int* __restrict__ k1, const int* __restrict__ v1,
    const int* __restrict__ k2, const int* __restrict__ v2,
    int* __restrict__ cur1, int* __restrict__ cur2,
    int* __restrict__ o1, int* __restrict__ o2,
    const u16* __restrict__ Aobj, const u16* __restrict__ w1t,
    const float* __restrict__ b1, u16* __restrict__ zobj)
{
  __shared__ u16 As[128 * 32];
  __shared__ u16 Bs[128 * 32];
  const int b = blockIdx.x, tid = threadIdx.x;
  if (b < 1536) {
    const int e = b * 256 + tid;
    if (e < E1CNT) { int p = atomicAdd(&cur1[k1[e]], 1); o1[p] = v1[e]; }
    else { const int i = e - E1CNT; int p = atomicAdd(&cur2[k2[i]], 1); o2[p] = v2[i]; }
    return;
  }
  const int g = b - 1536;
  const int m0 = (g >> 1) * 128;
  const int n0 = (g & 1) * 128;
  const int lane = tid & 63, wave = tid >> 6;
  const int wm = wave & 1, wn = wave >> 1;       // 2x2 wave grid
  f32x4 acc[4][4];
#pragma unroll
  for (int i = 0; i < 4; ++i)
#pragma unroll
    for (int j = 0; j < 4; ++j) { acc[i][j][0] = 0.f; acc[i][j][1] = 0.f; acc[i][j][2] = 0.f; acc[i][j][3] = 0.f; }

  for (int kc = 0; kc < 3; ++kc) {               // K = 96
    __syncthreads();
#pragma unroll
    for (int r = 0; r < 2; ++r) {
      const int u = r * 256 + tid;
      gload_lds16(Aobj + (size_t)(m0 + (u >> 2)) * 96 + kc * 32 + (u & 3) * 8,
                  As + (size_t)u * 8);
      gload_lds16(w1t + (size_t)(n0 + (u >> 2)) * 96 + kc * 32 + (u & 3) * 8,
                  Bs + (size_t)u * 8);
    }
    __syncthreads();
    bf16x8 a[4], bb[4];
#pragma unroll
    for (int i = 0; i < 4; ++i)
      a[i] = *(const bf16x8*)&As[(wm * 64 + 16 * i + (lane & 15)) * 32 + (lane >> 4) * 8];
#pragma unroll
    for (int j = 0; j < 4; ++j)
      bb[j] = *(const bf16x8*)&Bs[(wn * 64 + 16 * j + (lane & 15)) * 32 + (lane >> 4) * 8];
#pragma unroll
    for (int i = 0; i < 4; ++i)
#pragma unroll
      for (int j = 0; j < 4; ++j)
        acc[i][j] = __builtin_amdgcn_mfma_f32_16x16x32_bf16(a[i], bb[j], acc[i][j], 0, 0, 0);
  }
#pragma unroll
  for (int j = 0; j < 4; ++j) {
    const int c = n0 + wn * 64 + 16 * j + (lane & 15);
    const float bv = b1[c];
#pragma unroll
    for (int i = 0; i < 4; ++i) {
      const int rbase = m0 + wm * 64 + 16 * i + ((lane >> 4) << 2);
#pragma unroll
      for (int r = 0; r < 4; ++r)
        zobj[(size_t)(rbase + r) * 256 + c] = f2bf(acc[i][j][r] + bv);
    }
  }
}

// ---------------------------------------------------------------------------
// mid: per 32-agent tile (512 blocks, 4 waves -> 4 blocks/CU):
//   phase A: inline reduce1 -> s1 in LDS (eL, swizzled)
//   stage 1: enc = s1 @ W2 + deg*b2  -> encG (global bf16) + eL (overwrite)
//   stage 2: y2  = enc @ Wm + bm + pos@Wm[256:258] -> global bf16
// ---------------------------------------------------------------------------
__global__ __launch_bounds__(256) void k_mid(
    const u16* __restrict__ zobj, const float* __restrict__ agent_pos,
    const float* __restrict__ W1, const int* __restrict__ rp1,
    const int* __restrict__ sorted_obj,
    const u16* __restrict__ w2t, const u16* __restrict__ wmt,
    const float* __restrict__ b2, const float* __restrict__ bm,
    const float* __restrict__ Wm,
    u16* __restrict__ encG, u16* __restrict__ y2)
{
  __shared__ u16 Bs[256 * 32];
  __shared__ u16 eL[32 * 256];                   // s1, then enc (aliased)
  const int tid = threadIdx.x, lane = tid & 63, w = tid >> 6;
  const int m0 = blockIdx.x * 32;

  // ---- phase A: inline reduce1 (8 agents per wave) ------------------------
  {
    const float4 w0 = *(const float4*)(W1 + (size_t)64 * 256 + lane * 4);
    const float4 w1 = *(const float4*)(W1 + (size_t)65 * 256 + lane * 4);
    for (int q = 0; q < 8; ++q) {
      const int a = m0 + w * 8 + q;
      const float ax = agent_pos[(size_t)a * 2 + 0];
      const float ay = agent_pos[(size_t)a * 2 + 1];
      float r0, r1, r2, r3;
      seg_reduce_row(zobj, sorted_obj, rp1[a], rp1[a + 1], lane,
                     ax * w0.x + ay * w1.x, ax * w0.y + ay * w1.y,
                     ax * w0.z + ay * w1.z, ax * w0.w + ay * w1.w,
                     r0, r1, r2, r3);
      const int row = w * 8 + q;
      ushort4 o4; o4.x = f2bf(r0); o4.y = f2bf(r1); o4.z = f2bf(r2); o4.w = f2bf(r3);
      *(ushort4*)&eL[row * 256 + ((lane * 4) ^ ((row & 7) << 3))] = o4;
    }
  }
  __syncthreads();

  f32x4 acc[2][4];
  // ---- stage 1: s1 @ W2 ---------------------------------------------------
#pragma unroll
  for (int i = 0; i < 2; ++i)
#pragma unroll
    for (int j = 0; j < 4; ++j) { acc[i][j][0] = 0.f; acc[i][j][1] = 0.f; acc[i][j][2] = 0.f; acc[i][j][3] = 0.f; }
  for (int kc = 0; kc < 8; ++kc) {
    __syncthreads();
#pragma unroll
    for (int r = 0; r < 4; ++r) {
      const int u = r * 256 + tid;
      gload_lds16(w2t + (size_t)(u >> 2) * 256 + kc * 32 + (u & 3) * 8,
                  Bs + (size_t)u * 8);
    }
    __syncthreads();
    bf16x8 a[2], bb[4];
    const int col0 = kc * 32 + (lane >> 4) * 8;
#pragma unroll
    for (int i = 0; i < 2; ++i) {
      const int row = 16 * i + (lane & 15);
      a[i] = *(const bf16x8*)&eL[row * 256 + (col0 ^ ((row & 7) << 3))];
    }
#pragma unroll
    for (int j = 0; j < 4; ++j)
      bb[j] = *(const bf16x8*)&Bs[(w * 64 + 16 * j + (lane & 15)) * 32 + (lane >> 4) * 8];
#pragma unroll
    for (int i = 0; i < 2; ++i)
#pragma unroll
      for (int j = 0; j < 4; ++j)
        acc[i][j] = __builtin_amdgcn_mfma_f32_16x16x32_bf16(a[i], bb[j], acc[i][j], 0, 0, 0);
  }
  __syncthreads();                               // all eL(s1) reads done
  // epilogue1: enc = acc + deg*b2 -> encG + eL (swizzled)
#pragma unroll
  for (int i = 0; i < 2; ++i) {
    const int rb = 16 * i + ((lane >> 4) << 2);
    float deg[4];
#pragma unroll
    for (int r = 0; r < 4; ++r)
      deg[r] = (float)(rp1[m0 + rb + r + 1] - rp1[m0 + rb + r]);
#pragma unroll
    for (int j = 0; j < 4; ++j) {
      const int c = w * 64 + 16 * j + (lane & 15);
      const float bv = b2[c];
#pragma unroll
      for (int r = 0; r < 4; ++r) {
        const int row = rb + r;
        const u16 h = f2bf(acc[i][j][r] + deg[r] * bv);
        encG[(size_t)(m0 + row) * 256 + c] = h;
        eL[row * 256 + (c ^ ((row & 7) << 3))] = h;
      }
    }
  }
  __syncthreads();

  // ---- stage 2: enc @ Wm (+bm +pos@WmP) -----------------------------------
#pragma unroll
  for (int i = 0; i < 2; ++i)
#pragma unroll
    for (int j = 0; j < 4; ++j) { acc[i][j][0] = 0.f; acc[i][j][1] = 0.f; acc[i][j][2] = 0.f; acc[i][j][3] = 0.f; }
  for (int kc = 0; kc < 8; ++kc) {
    __syncthreads();
#pragma unroll
    for (int r = 0; r < 4; ++r) {
      const int u = r * 256 + tid;
      gload_lds16(wmt + (size_t)(u >> 2) * 256 + kc * 32 + (u & 3) * 8,
                  Bs + (size_t)u * 8);
    }
    __syncthreads();
    bf16x8 a[2], bb[4];
    const int col0 = kc * 32 + (lane >> 4) * 8;
#pragma unroll
    for (int i = 0; i < 2; ++i) {
      const int row = 16 * i + (lane & 15);
      a[i] = *(const bf16x8*)&eL[row * 256 + (col0 ^ ((row & 7) << 3))];
    }
#pragma unroll
    for (int j = 0; j < 4; ++j)
      bb[j] = *(const bf16x8*)&Bs[(w * 64 + 16 * j + (lane & 15)) * 32 + (lane >> 4) * 8];
#pragma unroll
    for (int i = 0; i < 2; ++i)
#pragma unroll
      for (int j = 0; j < 4; ++j)
        acc[i][j] = __builtin_amdgcn_mfma_f32_16x16x32_bf16(a[i], bb[j], acc[i][j], 0, 0, 0);
  }
  {
    const float* WmP = Wm + (size_t)256 * 256;
    float px[2][4], py[2][4];
#pragma unroll
    for (int i = 0; i < 2; ++i) {
      const int rb = 16 * i + ((lane >> 4) << 2);
#pragma unroll
      for (int r = 0; r < 4; ++r) {
        const float2 pp = *(const float2*)(agent_pos + (size_t)(m0 + rb + r) * 2);
        px[i][r] = pp.x; py[i][r] = pp.y;
      }
    }
#pragma unroll
    for (int j = 0; j < 4; ++j) {
      const int c = w * 64 + 16 * j + (lane & 15);
      const float w0c = WmP[c], w1c = WmP[256 + c], bmc = bm[c];
#pragma unroll
      for (int i = 0; i < 2; ++i) {
        const int rb = 16 * i + ((lane >> 4) << 2);
#pragma unroll
        for (int r = 0; r < 4; ++r)
          y2[(size_t)(m0 + rb + r) * 256 + c] =
              f2bf(acc[i][j][r] + bmc + px[i][r] * w0c + py[i][r] * w1c);
      }
    }
  }
}

// ---------------------------------------------------------------------------
// back: per 32-agent tile (512 blocks, 4 waves):
//   phase A: inline reduce2 -> agg in LDS (xL, swizzled)
//   stage 1: x = relu(encG@Wu[0:256] + agg@Wu[256:512] + bu)  (K=512 fused)
//   decode:  out = x @ Wd + bd (4x256 chunks + 128 tail) + fused batch write
// ---------------------------------------------------------------------------
__global__ __launch_bounds__(256) void k_back(
    const u16* __restrict__ y2, const float* __restrict__ agent_pos,
    const float* __restrict__ Wm, const int* __restrict__ rp2,
    const int* __restrict__ sorted_src,
    const u16* __restrict__ encG, const u16* __restrict__ wut,
    const u16* __restrict__ wdt, const float* __restrict__ bu,
    const float* __restrict__ bd, float* __restrict__ out)
{
  __shared__ u16 As[32 * 32];
  __shared__ u16 Bs[256 * 32];
  __shared__ u16 xL[32 * 256];                   // agg, then x (aliased)
  const int tid = threadIdx.x, lane = tid & 63, w = tid >> 6;
  const int m0 = blockIdx.x * 32;

  // ---- phase A: inline reduce2 (8 agents per wave) ------------------------
  {
    const float* WmP = Wm + (size_t)256 * 256;
    const float4 w0 = *(const float4*)(WmP + lane * 4);
    const float4 w1 = *(const float4*)(WmP + 256 + lane * 4);
    for (int q = 0; q < 8; ++q) {
      const int a = m0 + w * 8 + q;
      const float ax = agent_pos[(size_t)a * 2 + 0];
      const float ay = agent_pos[(size_t)a * 2 + 1];
      float r0, r1, r2, r3;
      seg_reduce_row(y2, sorted_src, rp2[a], rp2[a + 1], lane,
                     ax * w0.x + ay * w1.x, ax * w0.y + ay * w1.y,
                     ax * w0.z + ay * w1.z, ax * w0.w + ay * w1.w,
                     r0, r1, r2, r3);
      const int row = w * 8 + q;
      ushort4 o4; o4.x = f2bf(r0); o4.y = f2bf(r1); o4.z = f2bf(r2); o4.w = f2bf(r3);
      *(ushort4*)&xL[row * 256 + ((lane * 4) ^ ((row & 7) << 3))] = o4;
    }
  }
  __syncthreads();

  f32x4 acc[2][4];
  // ---- stage 1: [encG | agg] @ Wu, K = 512 --------------------------------
#pragma unroll
  for (int i = 0; i < 2; ++i)
#pragma unroll
    for (int j = 0; j < 4; ++j) { acc[i][j][0] = 0.f; acc[i][j][1] = 0.f; acc[i][j][2] = 0.f; acc[i][j][3] = 0.f; }
  for (int kc = 0; kc < 8; ++kc) {               // enc half (A staged from global)
    __syncthreads();
    if (tid < 128)
      gload_lds16(encG + (size_t)(m0 + (tid >> 2)) * 256 + kc * 32 + (tid & 3) * 8,
                  As + (size_t)tid * 8);
#pragma unroll
    for (int r = 0; r < 4; ++r) {
      const int u = r * 256 + tid;
      gload_lds16(wut + (size_t)(u >> 2) * 512 + kc * 32 + (u & 3) * 8,
                  Bs + (size_t)u * 8);
    }
    __syncthreads();
    bf16x8 a[2], bb[4];
#pragma unroll
    for (int i = 0; i < 2; ++i)
      a[i] = *(const bf16x8*)&As[(16 * i + (lane & 15)) * 32 + (lane >> 4) * 8];
#pragma unroll
    for (int j = 0; j < 4; ++j)
      bb[j] = *(const bf16x8*)&Bs[(w * 64 + 16 * j + (lane & 15)) * 32 + (lane >> 4) * 8];
#pragma unroll
    for (int i = 0; i < 2; ++i)
#pragma unroll
      for (int j = 0; j < 4; ++j)
        acc[i][j] = __builtin_amdgcn_mfma_f32_16x16x32_bf16(a[i], bb[j], acc[i][j], 0, 0, 0);
  }
  for (int kc = 8; kc < 16; ++kc) {              // agg half (A from LDS xL)
    __syncthreads();
#pragma unroll
    for (int r = 0; r < 4; ++r) {
      const int u = r * 256 + tid;
      gload_lds16(wut + (size_t)(u >> 2) * 512 + kc * 32 + (u & 3) * 8,
                  Bs + (size_t)u * 8);
    }
    __syncthreads();
    bf16x8 a[2], bb[4];
    const int col0 = (kc - 8) * 32 + (lane >> 4) * 8;
#pragma unroll
    for (int i = 0; i < 2; ++i) {
      const int row = 16 * i + (lane & 15);
      a[i] = *(const bf16x8*)&xL[row * 256 + (col0 ^ ((row & 7) << 3))];
    }
#pragma unroll
    for (int j = 0; j < 4; ++j)
      bb[j] = *(const bf16x8*)&Bs[(w * 64 + 16 * j + (lane & 15)) * 32 + (lane >> 4) * 8];
#pragma unroll
    for (int i = 0; i < 2; ++i)
#pragma unroll
      for (int j = 0; j < 4; ++j)
        acc[i][j] = __builtin_amdgcn_mfma_f32_16x16x32_bf16(a[i], bb[j], acc[i][j], 0, 0, 0);
  }
  __syncthreads();                               // all xL(agg) reads done
  // epilogue: x = relu(acc + bu) -> xL swizzled
#pragma unroll
  for (int j = 0; j < 4; ++j) {
    const int c = w * 64 + 16 * j + (lane & 15);
    const float bv = bu[c];
#pragma unroll
    for (int i = 0; i < 2; ++i) {
      const int rb = 16 * i + ((lane >> 4) << 2);
#pragma unroll
      for (int r = 0; r < 4; ++r) {
        const int row = rb + r;
        xL[row * 256 + (c ^ ((row & 7) << 3))] = f2bf(fmaxf(acc[i][j][r] + bv, 0.f));
      }
    }
  }
  __syncthreads();

  // ---- decode: 4 chunks of 256 cols ---------------------------------------
  for (int ch = 0; ch < 4; ++ch) {
#pragma unroll
    for (int i = 0; i < 2; ++i)
#pragma unroll
      for (int j = 0; j < 4; ++j) { acc[i][j][0] = 0.f; acc[i][j][1] = 0.f; acc[i][j][2] = 0.f; acc[i][j][3] = 0.f; }
    for (int kc = 0; kc < 8; ++kc) {
      __syncthreads();
#pragma unroll
      for (int r = 0; r < 4; ++r) {
        const int u = r * 256 + tid;
        gload_lds16(wdt + (size_t)(ch * 256 + (u >> 2)) * 256 + kc * 32 + (u & 3) * 8,
                    Bs + (size_t)u * 8);
      }
      __syncthreads();
      bf16x8 a[2], bb[4];
      const int col0 = kc * 32 + (lane >> 4) * 8;
#pragma unroll
      for (int i = 0; i < 2; ++i) {
        const int row = 16 * i + (lane & 15);
        a[i] = *(const bf16x8*)&xL[row * 256 + (col0 ^ ((row & 7) << 3))];
      }
#pragma unroll
      for (int j = 0; j < 4; ++j)
        bb[j] = *(const bf16x8*)&Bs[(w * 64 + 16 * j + (lane & 15)) * 32 + (lane >> 4) * 8];
#pragma unroll
      for (int i = 0; i < 2; ++i)
#pragma unroll
        for (int j = 0; j < 4; ++j)
          acc[i][j] = __builtin_amdgcn_mfma_f32_16x16x32_bf16(a[i], bb[j], acc[i][j], 0, 0, 0);
    }
#pragma unroll
    for (int j = 0; j < 4; ++j) {
      const int c = ch * 256 + w * 64 + 16 * j + (lane & 15);
      const float bv = bd[c];
#pragma unroll
      for (int i = 0; i < 2; ++i) {
        const int rb = 16 * i + ((lane >> 4) << 2);
#pragma unroll
        for (int r = 0; r < 4; ++r)
          out[(size_t)(m0 + rb + r) * NDEC + c] = acc[i][j][r] + bv;
      }
    }
  }

  // ---- decode tail: cols 1024..1151 (valid < 1056) ------------------------
  f32x4 acc3[2][2];
#pragma unroll
  for (int i = 0; i < 2; ++i)
#pragma unroll
    for (int j = 0; j < 2; ++j) { acc3[i][j][0] = 0.f; acc3[i][j][1] = 0.f; acc3[i][j][2] = 0.f; acc3[i][j][3] = 0.f; }
  for (int kc = 0; kc < 8; ++kc) {
    __syncthreads();
#pragma unroll
    for (int r = 0; r < 2; ++r) {
      const int u = r * 256 + tid;
      gload_lds16(wdt + (size_t)(1024 + (u >> 2)) * 256 + kc * 32 + (u & 3) * 8,
                  Bs + (size_t)u * 8);
    }
    __syncthreads();
    bf16x8 a[2], bb[2];
    const int col0 = kc * 32 + (lane >> 4) * 8;
#pragma unroll
    for (int i = 0; i < 2; ++i) {
      const int row = 16 * i + (lane & 15);
      a[i] = *(const bf16x8*)&xL[row * 256 + (col0 ^ ((row & 7) << 3))];
    }
#pragma unroll
    for (int j = 0; j < 2; ++j)
      bb[j] = *(const bf16x8*)&Bs[(w * 32 + 16 * j + (lane & 15)) * 32 + (lane >> 4) * 8];
#pragma unroll
    for (int i = 0; i < 2; ++i)
#pragma unroll
      for (int j = 0; j < 2; ++j)
        acc3[i][j] = __builtin_amdgcn_mfma_f32_16x16x32_bf16(a[i], bb[j], acc3[i][j], 0, 0, 0);
  }
#pragma unroll
  for (int j = 0; j < 2; ++j) {
    const int c = 1024 + w * 32 + 16 * j + (lane & 15);
    if (c < NDEC) {
      const float bv = bd[c];
#pragma unroll
      for (int i = 0; i < 2; ++i) {
        const int rb = 16 * i + ((lane >> 4) << 2);
#pragma unroll
        for (int r = 0; r < 4; ++r)
          out[(size_t)(m0 + rb + r) * NDEC + c] = acc3[i][j][r] + bv;
      }
    }
  }

  // ---- fused batch write: batch[i] = i >> 4 -------------------------------
  const size_t bb0 = DEC_OFF + (size_t)m0 * 16;
  const int i0 = tid * 2;
  out[bb0 + i0]     = (float)(m0 + (i0 >> 4));
  out[bb0 + i0 + 1] = (float)(m0 + ((i0 + 1) >> 4));
}

// ---------------------------------------------------------------------------
extern "C" void kernel_launch(void* const* d_in, const int* in_sizes, int n_in,
                              void* d_out, int out_size, void* d_ws, size_t ws_size,
                              hipStream_t stream) {
  const float* obj_x     = (const float*)d_in[0];
  const float* obj_pos   = (const float*)d_in[1];
  const float* agent_pos = (const float*)d_in[2];
  const int*   oae       = (const int*)d_in[3];
  const int*   ae        = (const int*)d_in[4];
  const float* W1 = (const float*)d_in[5];
  const float* b1 = (const float*)d_in[6];
  const float* W2 = (const float*)d_in[7];
  const float* b2 = (const float*)d_in[8];
  const float* Wm = (const float*)d_in[9];
  const float* bm = (const float*)d_in[10];
  const float* Wu = (const float*)d_in[11];
  const float* bu = (const float*)d_in[12];
  const float* Wd = (const float*)d_in[13];
  const float* bd = (const float*)d_in[14];
  float* out = (float*)d_out;

  const int* agent_idx = oae;
  const int* obj_idx   = oae + E1CNT;
  const int* src       = ae;
  const int* dst       = ae + E2CNT;

  // ---- workspace ---------------------------------------------------------
  char* p = (char*)d_ws;
  u16* slabA = (u16*)p; p += (size_t)NA * 256 * 2;      // Aobj(NOBJ*96) -> encG
  u16* zobj  = (u16*)p; p += (size_t)NOBJ * 256 * 2;
  u16* y2    = (u16*)p; p += (size_t)NA * 256 * 2;
  u16* w1t = (u16*)p; p += (size_t)256 * 96 * 2;
  u16* w2t = (u16*)p; p += (size_t)256 * 256 * 2;
  u16* wmt = (u16*)p; p += (size_t)256 * 256 * 2;
  u16* wut = (u16*)p; p += (size_t)256 * 512 * 2;
  u16* wdt = (u16*)p; p += (size_t)NDECP * 256 * 2;
  int* cur1 = (int*)p;           p += (size_t)NA * 4;   // cur1|cur2 adjacent
  int* cur2 = (int*)p;           p += (size_t)NA * 4;
  int* rp1  = (int*)p;           p += (size_t)(NA + 1) * 4;
  int* rp2  = (int*)p;           p += (size_t)(NA + 1) * 4;
  int* sorted_obj = (int*)p;     p += (size_t)E1CNT * 4;
  int* sorted_src = (int*)p;

  u16* Aobj = slabA;
  u16* encG = slabA;

  // ---- 6 dispatches ------------------------------------------------------
  hipMemsetAsync(cur1, 0, (size_t)2 * NA * sizeof(int), stream);
  k_front<<<3356, 256, 0, stream>>>(agent_idx, dst, cur1, cur2, obj_x, obj_pos,
      Aobj, W1, W2, Wm, Wu, Wd, w1t, w2t, wmt, wut, wdt);
  k_scan<<<2, 256, 0, stream>>>(cur1, rp1, cur2, rp2);
  k_fill_enc<<<2048, 256, 0, stream>>>(agent_idx, obj_idx, dst, src, cur1, cur2,
      sorted_obj, sorted_src, Aobj, w1t, b1, zobj);
  k_mid<<<NA / 32, 256, 0, stream>>>(zobj, agent_pos, W1, rp1, sorted_obj,
      w2t, wmt, b2, bm, Wm, encG, y2);
  k_back<<<NA / 32, 256, 0, stream>>>(y2, agent_pos, Wm, rp2, sorted_src,
      encG, wut, wdt, bu, bd, out);
}

// Round 3
// 252.126 us; speedup vs baseline: 1.0977x; 1.0977x over previous
//
#include <hip/hip_runtime.h>
#include <cstdint>
#include <cstddef>

#define EMB   256
#define NA    16384
#define NOBJ  32768
#define E1CNT 131072
#define E2CNT 262144
#define NDEC  1056
#define NDECP 1152
#define DEC_OFF ((size_t)NA * NDEC)

typedef unsigned short u16;
typedef __attribute__((ext_vector_type(8))) short bf16x8;
typedef __attribute__((ext_vector_type(8))) unsigned short u16x8;
typedef __attribute__((ext_vector_type(4))) float f32x4;

// ---------------------------------------------------------------------------
// bf16 helpers (RNE)
// ---------------------------------------------------------------------------
__device__ __forceinline__ u16 f2bf(float f) {
  union { float f; unsigned u; } x; x.f = f;
  unsigned u = x.u + 0x7FFFu + ((x.u >> 16) & 1u);
  return (u16)(u >> 16);
}
__device__ __forceinline__ float bf2f(u16 h) {
  union { unsigned u; float f; } x; x.u = ((unsigned)h) << 16;
  return x.f;
}

__device__ __forceinline__ void gload_lds16(const void* g, void* l) {
  __builtin_amdgcn_global_load_lds(
      (const __attribute__((address_space(1))) unsigned int*)g,
      (__attribute__((address_space(3))) unsigned int*)l, 16, 0, 0);
}

// [N][32] bf16 GEMM tiles (64B rows): LDS slot s at row r holds logical 16B
// chunk s ^ ((r>>1)&3) -> 16-lane phases cover 8 bank groups x2 (conflict-free).
// Staging source col chunk for linear dest u: (u&3) ^ ((u>>3)&3).
// Read offset for row R = 16*a + (lane&15), chunk lane>>4:
//   sq = ((lane>>4) ^ ((lane>>1)&3)) * 8   (elems; identical for all frags)

// ---------------------------------------------------------------------------
// inline segment reduce: r0..r3 = sum_e relu(vals[idx[e]][lane*4+r] - t_r)
// ---------------------------------------------------------------------------
__device__ __forceinline__ void seg_reduce_row(
    const u16* __restrict__ vals, const int* __restrict__ idx,
    int e0, int e1, int lane,
    float t0, float t1, float t2, float t3,
    float& r0, float& r1, float& r2, float& r3)
{
  float a0 = 0.f, a1 = 0.f, a2 = 0.f, a3 = 0.f;
  float b0 = 0.f, b1 = 0.f, b2 = 0.f, b3 = 0.f;
  int i = e0;
  for (; i + 3 < e1; i += 4) {
    const int o0 = idx[i], o1 = idx[i + 1], o2 = idx[i + 2], o3 = idx[i + 3];
    const ushort4 z0 = *(const ushort4*)(vals + (size_t)o0 * 256 + lane * 4);
    const ushort4 z1 = *(const ushort4*)(vals + (size_t)o1 * 256 + lane * 4);
    const ushort4 z2 = *(const ushort4*)(vals + (size_t)o2 * 256 + lane * 4);
    const ushort4 z3 = *(const ushort4*)(vals + (size_t)o3 * 256 + lane * 4);
    a0 += fmaxf(bf2f(z0.x) - t0, 0.f); a1 += fmaxf(bf2f(z0.y) - t1, 0.f);
    a2 += fmaxf(bf2f(z0.z) - t2, 0.f); a3 += fmaxf(bf2f(z0.w) - t3, 0.f);
    b0 += fmaxf(bf2f(z1.x) - t0, 0.f); b1 += fmaxf(bf2f(z1.y) - t1, 0.f);
    b2 += fmaxf(bf2f(z1.z) - t2, 0.f); b3 += fmaxf(bf2f(z1.w) - t3, 0.f);
    a0 += fmaxf(bf2f(z2.x) - t0, 0.f); a1 += fmaxf(bf2f(z2.y) - t1, 0.f);
    a2 += fmaxf(bf2f(z2.z) - t2, 0.f); a3 += fmaxf(bf2f(z2.w) - t3, 0.f);
    b0 += fmaxf(bf2f(z3.x) - t0, 0.f); b1 += fmaxf(bf2f(z3.y) - t1, 0.f);
    b2 += fmaxf(bf2f(z3.z) - t2, 0.f); b3 += fmaxf(bf2f(z3.w) - t3, 0.f);
  }
  for (; i < e1; ++i) {
    const int o = idx[i];
    const ushort4 z = *(const ushort4*)(vals + (size_t)o * 256 + lane * 4);
    a0 += fmaxf(bf2f(z.x) - t0, 0.f); a1 += fmaxf(bf2f(z.y) - t1, 0.f);
    a2 += fmaxf(bf2f(z.z) - t2, 0.f); a3 += fmaxf(bf2f(z.w) - t3, 0.f);
  }
  r0 = a0 + b0; r1 = a1 + b1; r2 = a2 + b2; r3 = a3 + b3;
}

// ---------------------------------------------------------------------------
// front: CSR count + obj prep (bf16, 8-wide) + all weight cvt/transpose
// blocks [0,1536): count | [1536,3072): prep | [3072,3356): cvt
// ---------------------------------------------------------------------------
__global__ __launch_bounds__(256) void k_front(
    const int* __restrict__ k1, const int* __restrict__ k2,
    int* __restrict__ c1, int* __restrict__ c2,
    const float* __restrict__ obj_x, const float* __restrict__ obj_pos,
    u16* __restrict__ Aobj,
    const float* __restrict__ W1, const float* __restrict__ W2,
    const float* __restrict__ Wm, const float* __restrict__ Wu,
    const float* __restrict__ Wd,
    u16* __restrict__ w1t, u16* __restrict__ w2t, u16* __restrict__ wmt,
    u16* __restrict__ wut, u16* __restrict__ wdt)
{
  const int b = blockIdx.x, tid = threadIdx.x;
  if (b < 1536) {                                  // edge counting
    const int e = b * 256 + tid;
    if (e < E1CNT) atomicAdd(&c1[k1[e]], 1);
    else           atomicAdd(&c2[k2[e - E1CNT]], 1);
    return;
  }
  if (b < 3072) {                                  // Aobj[o][96] = [x|pos|0]
    const int g = (b - 1536) * 256 + tid;
    const int row = g / 12, seg = g - row * 12;
    u16x8 o;
    if (seg < 8) {
      const float4 f0 = *(const float4*)(obj_x + (size_t)row * 64 + seg * 8);
      const float4 f1 = *(const float4*)(obj_x + (size_t)row * 64 + seg * 8 + 4);
      o[0] = f2bf(f0.x); o[1] = f2bf(f0.y); o[2] = f2bf(f0.z); o[3] = f2bf(f0.w);
      o[4] = f2bf(f1.x); o[5] = f2bf(f1.y); o[6] = f2bf(f1.z); o[7] = f2bf(f1.w);
    } else if (seg == 8) {
      const float2 pp = *(const float2*)(obj_pos + (size_t)row * 2);
      o[0] = f2bf(pp.x); o[1] = f2bf(pp.y);
      o[2] = 0; o[3] = 0; o[4] = 0; o[5] = 0; o[6] = 0; o[7] = 0;
    } else {
#pragma unroll
      for (int t = 0; t < 8; ++t) o[t] = 0;
    }
    *(u16x8*)(Aobj + (size_t)row * 96 + seg * 8) = o;
    return;
  }
  // weight transpose+cvt; boundaries in 8-elem units
  int l = (b - 3072) * 256 + tid;
  const float* W; u16* WT; int Ko, No, Kp8;
  if      (l < 3072)  { W = W1; WT = w1t; Ko = 66;  No = 256;  Kp8 = 12; }
  else if (l < 11264) { W = W2; WT = w2t; Ko = 256; No = 256;  Kp8 = 32; l -= 3072; }
  else if (l < 19456) { W = Wm; WT = wmt; Ko = 256; No = 256;  Kp8 = 32; l -= 11264; }
  else if (l < 35840) { W = Wu; WT = wut; Ko = 512; No = 256;  Kp8 = 64; l -= 19456; }
  else                { W = Wd; WT = wdt; Ko = 256; No = 1056; Kp8 = 32; l -= 35840; }
  const int n = l / Kp8, k0 = (l - n * Kp8) * 8;
  u16x8 o;
#pragma unroll
  for (int t = 0; t < 8; ++t) {
    const int k = k0 + t;
    const float v = (k < Ko && n < No) ? W[(size_t)k * No + n] : 0.f;
    o[t] = f2bf(v);
  }
  *(u16x8*)(WT + (size_t)n * (Kp8 * 8) + k0) = o;
}

// ---------------------------------------------------------------------------
// prefix scan of both count arrays
// ---------------------------------------------------------------------------
__global__ __launch_bounds__(256) void k_scan(int* c1, int* r1, int* c2, int* r2) {
  int* cnt = (blockIdx.x == 0) ? c1 : c2;
  int* rp  = (blockIdx.x == 0) ? r1 : r2;
  const int n = NA;
  __shared__ int partial[256];
  const int tid = threadIdx.x;
  const int base = tid * 64;
  int local[64];
  int s = 0;
#pragma unroll
  for (int i = 0; i < 64; ++i) { local[i] = s; s += cnt[base + i]; }
  partial[tid] = s;
  __syncthreads();
  for (int off = 1; off < 256; off <<= 1) {
    int v = (tid >= off) ? partial[tid - off] : 0;
    __syncthreads();
    partial[tid] += v;
    __syncthreads();
  }
  const int offset = (tid == 0) ? 0 : partial[tid - 1];
#pragma unroll
  for (int i = 0; i < 64; ++i) {
    int v = offset + local[i];
    rp[base + i]  = v;
    cnt[base + i] = v;
  }
  if (tid == 255) rp[n] = partial[255];
}

// ---------------------------------------------------------------------------
// fill CSR + encode GEMM (zobj = [obj_x|obj_pos|0] @ W1 + b1) in ONE dispatch
// 256-thread blocks: [0,1536) fill | [1536,2048): 128x128 GEMM tiles
// ---------------------------------------------------------------------------
__global__ __launch_bounds__(256) void k_fill_enc(
    const int* __restrict__ k1, const int* __restrict__ v1,
    const int* __restrict__ k2, const int* __restrict__ v2,
    int* __restrict__ cur1, int* __restrict__ cur2,
    int* __restrict__ o1, int* __restrict__ o2,
    const u16* __restrict__ Aobj, const u16* __restrict__ w1t,
    const float* __restrict__ b1, u16* __restrict__ zobj)
{
  __shared__ u16 As[128 * 32];
  __shared__ u16 Bs[128 * 32];
  const int b = blockIdx.x, tid = threadIdx.x;
  if (b < 1536) {
    const int e = b * 256 + tid;
    if (e < E1CNT) { int p = atomicAdd(&cur1[k1[e]], 1); o1[p] = v1[e]; }
    else { const int i = e - E1CNT; int p = atomicAdd(&cur2[k2[i]], 1); o2[p] = v2[i]; }
    return;
  }
  const int g = b - 1536;
  const int m0 = (g >> 1) * 128;
  const int n0 = (g & 1) * 128;
  const int lane = tid & 63, wave = tid >> 6;
  const int wm = wave & 1, wn = wave >> 1;       // 2x2 wave grid
  const int sq = ((lane >> 4) ^ ((lane >> 1) & 3)) * 8;
  f32x4 acc[4][4];
#pragma unroll
  for (int i = 0; i < 4; ++i)
#pragma unroll
    for (int j = 0; j < 4; ++j) { acc[i][j][0] = 0.f; acc[i][j][1] = 0.f; acc[i][j][2] = 0.f; acc[i][j][3] = 0.f; }

  for (int kc = 0; kc < 3; ++kc) {               // K = 96
    __syncthreads();
#pragma unroll
    for (int r = 0; r < 2; ++r) {
      const int u = r * 256 + tid;
      const int js = ((u & 3) ^ ((u >> 3) & 3)) * 8;
      gload_lds16(Aobj + (size_t)(m0 + (u >> 2)) * 96 + kc * 32 + js,
                  As + (size_t)u * 8);
      gload_lds16(w1t + (size_t)(n0 + (u >> 2)) * 96 + kc * 32 + js,
                  Bs + (size_t)u * 8);
    }
    __syncthreads();
    bf16x8 a[4], bb[4];
#pragma unroll
    for (int i = 0; i < 4; ++i)
      a[i] = *(const bf16x8*)&As[(wm * 64 + 16 * i + (lane & 15)) * 32 + sq];
#pragma unroll
    for (int j = 0; j < 4; ++j)
      bb[j] = *(const bf16x8*)&Bs[(wn * 64 + 16 * j + (lane & 15)) * 32 + sq];
#pragma unroll
    for (int i = 0; i < 4; ++i)
#pragma unroll
      for (int j = 0; j < 4; ++j)
        acc[i][j] = __builtin_amdgcn_mfma_f32_16x16x32_bf16(a[i], bb[j], acc[i][j], 0, 0, 0);
  }
#pragma unroll
  for (int j = 0; j < 4; ++j) {
    const int c = n0 + wn * 64 + 16 * j + (lane & 15);
    const float bv = b1[c];
#pragma unroll
    for (int i = 0; i < 4; ++i) {
      const int rbase = m0 + wm * 64 + 16 * i + ((lane >> 4) << 2);
#pragma unroll
      for (int r = 0; r < 4; ++r)
        zobj[(size_t)(rbase + r) * 256 + c] = f2bf(acc[i][j][r] + bv);
    }
  }
}

// ---------------------------------------------------------------------------
// mid: per 32-agent tile, 512 threads (8 waves -> 16 waves/CU):
//   phase A: inline reduce1 -> s1 in LDS (eL, swizzled)
//   stage 1: enc = s1 @ W2 + deg*b2  -> encG (global bf16) + eL (overwrite)
//   stage 2: y2  = enc @ Wm + bm + pos@Wm[256:258] -> global bf16
// ---------------------------------------------------------------------------
__global__ __launch_bounds__(512) void k_mid(
    const u16* __restrict__ zobj, const float* __restrict__ agent_pos,
    const float* __restrict__ W1, const int* __restrict__ rp1,
    const int* __restrict__ sorted_obj,
    const u16* __restrict__ w2t, const u16* __restrict__ wmt,
    const float* __restrict__ b2, const float* __restrict__ bm,
    const float* __restrict__ Wm,
    u16* __restrict__ encG, u16* __restrict__ y2)
{
  __shared__ u16 Bs[256 * 32];
  __shared__ u16 eL[32 * 256];                   // s1, then enc (aliased)
  const int tid = threadIdx.x, lane = tid & 63, w = tid >> 6;
  const int m0 = blockIdx.x * 32;
  const int sq = ((lane >> 4) ^ ((lane >> 1) & 3)) * 8;

  // ---- phase A: inline reduce1 (4 agents per wave) ------------------------
  {
    const float4 w0 = *(const float4*)(W1 + (size_t)64 * 256 + lane * 4);
    const float4 w1 = *(const float4*)(W1 + (size_t)65 * 256 + lane * 4);
    for (int q = 0; q < 4; ++q) {
      const int a = m0 + w * 4 + q;
      const float ax = agent_pos[(size_t)a * 2 + 0];
      const float ay = agent_pos[(size_t)a * 2 + 1];
      float r0, r1, r2, r3;
      seg_reduce_row(zobj, sorted_obj, rp1[a], rp1[a + 1], lane,
                     ax * w0.x + ay * w1.x, ax * w0.y + ay * w1.y,
                     ax * w0.z + ay * w1.z, ax * w0.w + ay * w1.w,
                     r0, r1, r2, r3);
      const int row = w * 4 + q;
      ushort4 o4; o4.x = f2bf(r0); o4.y = f2bf(r1); o4.z = f2bf(r2); o4.w = f2bf(r3);
      *(ushort4*)&eL[row * 256 + ((lane * 4) ^ ((row & 7) << 3))] = o4;
    }
  }
  __syncthreads();

  f32x4 acc[2][2];
  // ---- stage 1: s1 @ W2 ---------------------------------------------------
#pragma unroll
  for (int i = 0; i < 2; ++i)
#pragma unroll
    for (int j = 0; j < 2; ++j) { acc[i][j][0] = 0.f; acc[i][j][1] = 0.f; acc[i][j][2] = 0.f; acc[i][j][3] = 0.f; }
  for (int kc = 0; kc < 8; ++kc) {
    __syncthreads();
#pragma unroll
    for (int r = 0; r < 2; ++r) {
      const int u = r * 512 + tid;
      gload_lds16(w2t + (size_t)(u >> 2) * 256 + kc * 32 + ((u & 3) ^ ((u >> 3) & 3)) * 8,
                  Bs + (size_t)u * 8);
    }
    __syncthreads();
    bf16x8 a[2], bb[2];
    const int col0 = kc * 32 + (lane >> 4) * 8;
#pragma unroll
    for (int i = 0; i < 2; ++i) {
      const int row = 16 * i + (lane & 15);
      a[i] = *(const bf16x8*)&eL[row * 256 + (col0 ^ ((row & 7) << 3))];
    }
#pragma unroll
    for (int j = 0; j < 2; ++j)
      bb[j] = *(const bf16x8*)&Bs[(w * 32 + 16 * j + (lane & 15)) * 32 + sq];
#pragma unroll
    for (int i = 0; i < 2; ++i)
#pragma unroll
      for (int j = 0; j < 2; ++j)
        acc[i][j] = __builtin_amdgcn_mfma_f32_16x16x32_bf16(a[i], bb[j], acc[i][j], 0, 0, 0);
  }
  __syncthreads();                               // all eL(s1) reads done
  // epilogue1: enc = acc + deg*b2 -> encG + eL (swizzled)
#pragma unroll
  for (int i = 0; i < 2; ++i) {
    const int rb = 16 * i + ((lane >> 4) << 2);
    float deg[4];
#pragma unroll
    for (int r = 0; r < 4; ++r)
      deg[r] = (float)(rp1[m0 + rb + r + 1] - rp1[m0 + rb + r]);
#pragma unroll
    for (int j = 0; j < 2; ++j) {
      const int c = w * 32 + 16 * j + (lane & 15);
      const float bv = b2[c];
#pragma unroll
      for (int r = 0; r < 4; ++r) {
        const int row = rb + r;
        const u16 h = f2bf(acc[i][j][r] + deg[r] * bv);
        encG[(size_t)(m0 + row) * 256 + c] = h;
        eL[row * 256 + (c ^ ((row & 7) << 3))] = h;
      }
    }
  }
  __syncthreads();

  // ---- stage 2: enc @ Wm (+bm +pos@WmP) -----------------------------------
#pragma unroll
  for (int i = 0; i < 2; ++i)
#pragma unroll
    for (int j = 0; j < 2; ++j) { acc[i][j][0] = 0.f; acc[i][j][1] = 0.f; acc[i][j][2] = 0.f; acc[i][j][3] = 0.f; }
  for (int kc = 0; kc < 8; ++kc) {
    __syncthreads();
#pragma unroll
    for (int r = 0; r < 2; ++r) {
      const int u = r * 512 + tid;
      gload_lds16(wmt + (size_t)(u >> 2) * 256 + kc * 32 + ((u & 3) ^ ((u >> 3) & 3)) * 8,
                  Bs + (size_t)u * 8);
    }
    __syncthreads();
    bf16x8 a[2], bb[2];
    const int col0 = kc * 32 + (lane >> 4) * 8;
#pragma unroll
    for (int i = 0; i < 2; ++i) {
      const int row = 16 * i + (lane & 15);
      a[i] = *(const bf16x8*)&eL[row * 256 + (col0 ^ ((row & 7) << 3))];
    }
#pragma unroll
    for (int j = 0; j < 2; ++j)
      bb[j] = *(const bf16x8*)&Bs[(w * 32 + 16 * j + (lane & 15)) * 32 + sq];
#pragma unroll
    for (int i = 0; i < 2; ++i)
#pragma unroll
      for (int j = 0; j < 2; ++j)
        acc[i][j] = __builtin_amdgcn_mfma_f32_16x16x32_bf16(a[i], bb[j], acc[i][j], 0, 0, 0);
  }
  {
    const float* WmP = Wm + (size_t)256 * 256;
    float px[2][4], py[2][4];
#pragma unroll
    for (int i = 0; i < 2; ++i) {
      const int rb = 16 * i + ((lane >> 4) << 2);
#pragma unroll
      for (int r = 0; r < 4; ++r) {
        const float2 pp = *(const float2*)(agent_pos + (size_t)(m0 + rb + r) * 2);
        px[i][r] = pp.x; py[i][r] = pp.y;
      }
    }
#pragma unroll
    for (int j = 0; j < 2; ++j) {
      const int c = w * 32 + 16 * j + (lane & 15);
      const float w0c = WmP[c], w1c = WmP[256 + c], bmc = bm[c];
#pragma unroll
      for (int i = 0; i < 2; ++i) {
        const int rb = 16 * i + ((lane >> 4) << 2);
#pragma unroll
        for (int r = 0; r < 4; ++r)
          y2[(size_t)(m0 + rb + r) * 256 + c] =
              f2bf(acc[i][j][r] + bmc + px[i][r] * w0c + py[i][r] * w1c);
      }
    }
  }
}

// ---------------------------------------------------------------------------
// upd: per 32-agent tile, 512 threads (8 waves):
//   phase A: inline reduce2 -> agg in LDS (xL, swizzled)
//   stage 1: x = relu(encG@Wu[0:256] + agg@Wu[256:512] + bu) -> xg (global)
// ---------------------------------------------------------------------------
__global__ __launch_bounds__(512) void k_upd(
    const u16* __restrict__ y2, const float* __restrict__ agent_pos,
    const float* __restrict__ Wm, const int* __restrict__ rp2,
    const int* __restrict__ sorted_src,
    const u16* __restrict__ encG, const u16* __restrict__ wut,
    const float* __restrict__ bu, u16* __restrict__ xg)
{
  __shared__ u16 As[32 * 32];
  __shared__ u16 Bs[256 * 32];
  __shared__ u16 xL[32 * 256];
  const int tid = threadIdx.x, lane = tid & 63, w = tid >> 6;
  const int m0 = blockIdx.x * 32;
  const int sq = ((lane >> 4) ^ ((lane >> 1) & 3)) * 8;

  // ---- phase A: inline reduce2 (4 agents per wave) ------------------------
  {
    const float* WmP = Wm + (size_t)256 * 256;
    const float4 w0 = *(const float4*)(WmP + lane * 4);
    const float4 w1 = *(const float4*)(WmP + 256 + lane * 4);
    for (int q = 0; q < 4; ++q) {
      const int a = m0 + w * 4 + q;
      const float ax = agent_pos[(size_t)a * 2 + 0];
      const float ay = agent_pos[(size_t)a * 2 + 1];
      float r0, r1, r2, r3;
      seg_reduce_row(y2, sorted_src, rp2[a], rp2[a + 1], lane,
                     ax * w0.x + ay * w1.x, ax * w0.y + ay * w1.y,
                     ax * w0.z + ay * w1.z, ax * w0.w + ay * w1.w,
                     r0, r1, r2, r3);
      const int row = w * 4 + q;
      ushort4 o4; o4.x = f2bf(r0); o4.y = f2bf(r1); o4.z = f2bf(r2); o4.w = f2bf(r3);
      *(ushort4*)&xL[row * 256 + ((lane * 4) ^ ((row & 7) << 3))] = o4;
    }
  }
  __syncthreads();

  f32x4 acc[2][2];
#pragma unroll
  for (int i = 0; i < 2; ++i)
#pragma unroll
    for (int j = 0; j < 2; ++j) { acc[i][j][0] = 0.f; acc[i][j][1] = 0.f; acc[i][j][2] = 0.f; acc[i][j][3] = 0.f; }
  for (int kc = 0; kc < 8; ++kc) {               // enc half (A from global)
    __syncthreads();
    if (tid < 128)
      gload_lds16(encG + (size_t)(m0 + (tid >> 2)) * 256 + kc * 32 + ((tid & 3) ^ ((tid >> 3) & 3)) * 8,
                  As + (size_t)tid * 8);
#pragma unroll
    for (int r = 0; r < 2; ++r) {
      const int u = r * 512 + tid;
      gload_lds16(wut + (size_t)(u >> 2) * 512 + kc * 32 + ((u & 3) ^ ((u >> 3) & 3)) * 8,
                  Bs + (size_t)u * 8);
    }
    __syncthreads();
    bf16x8 a[2], bb[2];
#pragma unroll
    for (int i = 0; i < 2; ++i)
      a[i] = *(const bf16x8*)&As[(16 * i + (lane & 15)) * 32 + sq];
#pragma unroll
    for (int j = 0; j < 2; ++j)
      bb[j] = *(const bf16x8*)&Bs[(w * 32 + 16 * j + (lane & 15)) * 32 + sq];
#pragma unroll
    for (int i = 0; i < 2; ++i)
#pragma unroll
      for (int j = 0; j < 2; ++j)
        acc[i][j] = __builtin_amdgcn_mfma_f32_16x16x32_bf16(a[i], bb[j], acc[i][j], 0, 0, 0);
  }
  for (int kc = 8; kc < 16; ++kc) {              // agg half (A from LDS xL)
    __syncthreads();
#pragma unroll
    for (int r = 0; r < 2; ++r) {
      const int u = r * 512 + tid;
      gload_lds16(wut + (size_t)(u >> 2) * 512 + kc * 32 + ((u & 3) ^ ((u >> 3) & 3)) * 8,
                  Bs + (size_t)u * 8);
    }
    __syncthreads();
    bf16x8 a[2], bb[2];
    const int col0 = (kc - 8) * 32 + (lane >> 4) * 8;
#pragma unroll
    for (int i = 0; i < 2; ++i) {
      const int row = 16 * i + (lane & 15);
      a[i] = *(const bf16x8*)&xL[row * 256 + (col0 ^ ((row & 7) << 3))];
    }
#pragma unroll
    for (int j = 0; j < 2; ++j)
      bb[j] = *(const bf16x8*)&Bs[(w * 32 + 16 * j + (lane & 15)) * 32 + sq];
#pragma unroll
    for (int i = 0; i < 2; ++i)
#pragma unroll
      for (int j = 0; j < 2; ++j)
        acc[i][j] = __builtin_amdgcn_mfma_f32_16x16x32_bf16(a[i], bb[j], acc[i][j], 0, 0, 0);
  }
  // epilogue: x = relu(acc + bu) -> xg global
#pragma unroll
  for (int j = 0; j < 2; ++j) {
    const int c = w * 32 + 16 * j + (lane & 15);
    const float bv = bu[c];
#pragma unroll
    for (int i = 0; i < 2; ++i) {
      const int rb = 16 * i + ((lane >> 4) << 2);
#pragma unroll
      for (int r = 0; r < 4; ++r)
        xg[(size_t)(m0 + rb + r) * 256 + c] = f2bf(fmaxf(acc[i][j][r] + bv, 0.f));
    }
  }
}

// ---------------------------------------------------------------------------
// dec: m97-style 128x128 GEMM, grid (NA/128, NDECP/128) = 128 x 9 blocks
//   out = x @ Wd + bd (fp32), + fused batch write on col-tile 0
// ---------------------------------------------------------------------------
__global__ __launch_bounds__(256) void k_dec(
    const u16* __restrict__ xg, const u16* __restrict__ wdt,
    const float* __restrict__ bd, float* __restrict__ out)
{
  __shared__ u16 As[128 * 32];
  __shared__ u16 Bs[128 * 32];
  const int tid = threadIdx.x, lane = tid & 63, wave = tid >> 6;
  const int wm = wave & 1, wn = wave >> 1;       // 2x2 wave grid
  const int m0 = blockIdx.x * 128, n0 = blockIdx.y * 128;
  const int sq = ((lane >> 4) ^ ((lane >> 1) & 3)) * 8;
  f32x4 acc[4][4];
#pragma unroll
  for (int i = 0; i < 4; ++i)
#pragma unroll
    for (int j = 0; j < 4; ++j) { acc[i][j][0] = 0.f; acc[i][j][1] = 0.f; acc[i][j][2] = 0.f; acc[i][j][3] = 0.f; }

  for (int kc = 0; kc < 8; ++kc) {
    __syncthreads();
#pragma unroll
    for (int r = 0; r < 2; ++r) {
      const int u = r * 256 + tid;
      const int js = ((u & 3) ^ ((u >> 3) & 3)) * 8;
      gload_lds16(xg + (size_t)(m0 + (u >> 2)) * 256 + kc * 32 + js,
                  As + (size_t)u * 8);
      gload_lds16(wdt + (size_t)(n0 + (u >> 2)) * 256 + kc * 32 + js,
                  Bs + (size_t)u * 8);
    }
    __syncthreads();
    bf16x8 a[4], bb[4];
#pragma unroll
    for (int i = 0; i < 4; ++i)
      a[i] = *(const bf16x8*)&As[(wm * 64 + 16 * i + (lane & 15)) * 32 + sq];
#pragma unroll
    for (int j = 0; j < 4; ++j)
      bb[j] = *(const bf16x8*)&Bs[(wn * 64 + 16 * j + (lane & 15)) * 32 + sq];
#pragma unroll
    for (int i = 0; i < 4; ++i)
#pragma unroll
      for (int j = 0; j < 4; ++j)
        acc[i][j] = __builtin_amdgcn_mfma_f32_16x16x32_bf16(a[i], bb[j], acc[i][j], 0, 0, 0);
  }

#pragma unroll
  for (int j = 0; j < 4; ++j) {
    const int c = n0 + wn * 64 + 16 * j + (lane & 15);
    if (c < NDEC) {
      const float bv = bd[c];
#pragma unroll
      for (int i = 0; i < 4; ++i) {
        const int rbase = m0 + wm * 64 + 16 * i + ((lane >> 4) << 2);
#pragma unroll
        for (int r = 0; r < 4; ++r)
          out[(size_t)(rbase + r) * NDEC + c] = acc[i][j][r] + bv;
      }
    }
  }

  // fused batch write: batch[i] = i >> 4 for rows [m0, m0+128)
  if (blockIdx.y == 0) {
    const size_t bb0 = DEC_OFF + (size_t)m0 * 16;
#pragma unroll
    for (int t = 0; t < 8; ++t) {
      const int idx = tid * 8 + t;
      out[bb0 + idx] = (float)(m0 + (idx >> 4));
    }
  }
}

// ---------------------------------------------------------------------------
extern "C" void kernel_launch(void* const* d_in, const int* in_sizes, int n_in,
                              void* d_out, int out_size, void* d_ws, size_t ws_size,
                              hipStream_t stream) {
  const float* obj_x     = (const float*)d_in[0];
  const float* obj_pos   = (const float*)d_in[1];
  const float* agent_pos = (const float*)d_in[2];
  const int*   oae       = (const int*)d_in[3];
  const int*   ae        = (const int*)d_in[4];
  const float* W1 = (const float*)d_in[5];
  const float* b1 = (const float*)d_in[6];
  const float* W2 = (const float*)d_in[7];
  const float* b2 = (const float*)d_in[8];
  const float* Wm = (const float*)d_in[9];
  const float* bm = (const float*)d_in[10];
  const float* Wu = (const float*)d_in[11];
  const float* bu = (const float*)d_in[12];
  const float* Wd = (const float*)d_in[13];
  const float* bd = (const float*)d_in[14];
  float* out = (float*)d_out;

  const int* agent_idx = oae;
  const int* obj_idx   = oae + E1CNT;
  const int* src       = ae;
  const int* dst       = ae + E2CNT;

  // ---- workspace ---------------------------------------------------------
  char* p = (char*)d_ws;
  u16* slabA = (u16*)p; p += (size_t)NA * 256 * 2;      // Aobj(NOBJ*96) -> encG
  u16* zobj  = (u16*)p; p += (size_t)NOBJ * 256 * 2;    // zobj; 2nd half -> xg
  u16* y2    = (u16*)p; p += (size_t)NA * 256 * 2;
  u16* w1t = (u16*)p; p += (size_t)256 * 96 * 2;
  u16* w2t = (u16*)p; p += (size_t)256 * 256 * 2;
  u16* wmt = (u16*)p; p += (size_t)256 * 256 * 2;
  u16* wut = (u16*)p; p += (size_t)256 * 512 * 2;
  u16* wdt = (u16*)p; p += (size_t)NDECP * 256 * 2;
  int* cur1 = (int*)p;           p += (size_t)NA * 4;   // cur1|cur2 adjacent
  int* cur2 = (int*)p;           p += (size_t)NA * 4;
  int* rp1  = (int*)p;           p += (size_t)(NA + 1) * 4;
  int* rp2  = (int*)p;           p += (size_t)(NA + 1) * 4;
  int* sorted_obj = (int*)p;     p += (size_t)E1CNT * 4;
  int* sorted_src = (int*)p;

  u16* Aobj = slabA;
  u16* encG = slabA;
  u16* xg   = zobj + (size_t)NA * 256;   // zobj dead after k_mid phase A

  // ---- 7 dispatches ------------------------------------------------------
  hipMemsetAsync(cur1, 0, (size_t)2 * NA * sizeof(int), stream);
  k_front<<<3356, 256, 0, stream>>>(agent_idx, dst, cur1, cur2, obj_x, obj_pos,
      Aobj, W1, W2, Wm, Wu, Wd, w1t, w2t, wmt, wut, wdt);
  k_scan<<<2, 256, 0, stream>>>(cur1, rp1, cur2, rp2);
  k_fill_enc<<<2048, 256, 0, stream>>>(agent_idx, obj_idx, dst, src, cur1, cur2,
      sorted_obj, sorted_src, Aobj, w1t, b1, zobj);
  k_mid<<<NA / 32, 512, 0, stream>>>(zobj, agent_pos, W1, rp1, sorted_obj,
      w2t, wmt, b2, bm, Wm, encG, y2);
  k_upd<<<NA / 32, 512, 0, stream>>>(y2, agent_pos, Wm, rp2, sorted_src,
      encG, wut, bu, xg);
  k_dec<<<dim3(NA / 128, NDECP / 128), 256, 0, stream>>>(xg, wdt, bd, out);
}